// Round 1
// baseline (310.909 us; speedup 1.0000x reference)
//
#include <hip/hip_runtime.h>

typedef float f32x4 __attribute__((ext_vector_type(4)));
typedef long i64;

#define FP8_MAX 448.0f

// ---------------------------------------------------------------------------
// Activation quant: per (row, 128-elem K-block): s = max|x|/448, q = fp8(x/s).
// Writes xq [M][K] fp8 bytes and xst TRANSPOSED scales [K/128][M] (so the GEMM
// epilogue can read 4 consecutive rows' scales as one float4).
// One 32-lane half-wave per 128-elem block; float4 per lane.
// ---------------------------------------------------------------------------
__global__ __launch_bounds__(256) void act_quant_k(const float* __restrict__ x,
                                                   unsigned char* __restrict__ xq,
                                                   float* __restrict__ xst,
                                                   int M, int K) {
    const int t   = threadIdx.x;
    const int qb  = blockIdx.x * 8 + (t >> 5);   // global 128-block id
    const int l32 = t & 31;
    const int row = qb >> 5;                     // K/128 == 32 blocks per row
    const int kb  = qb & 31;
    const size_t base = (size_t)row * K + (size_t)kb * 128 + (size_t)l32 * 4;

    float4 v = *(const float4*)(x + base);
    float am = fmaxf(fmaxf(fabsf(v.x), fabsf(v.y)), fmaxf(fabsf(v.z), fabsf(v.w)));
#pragma unroll
    for (int off = 1; off < 32; off <<= 1)
        am = fmaxf(am, __shfl_xor(am, off, 64));

    const float s = am / FP8_MAX;                // fp32 IEEE div, matches reference
    const float q0 = v.x / s, q1 = v.y / s, q2 = v.z / s, q3 = v.w / s;
    int p = __builtin_amdgcn_cvt_pk_fp8_f32(q0, q1, 0, false);
    p     = __builtin_amdgcn_cvt_pk_fp8_f32(q2, q3, p, true);
    *(int*)(xq + base) = p;
    if (l32 == 0) xst[(size_t)kb * M + row] = s;
}

// ---------------------------------------------------------------------------
// Weight fp32 -> fp8 byte conversion (values are already on the e4m3 grid,
// so this conversion is exact).
// ---------------------------------------------------------------------------
__global__ __launch_bounds__(256) void wq_cvt_k(const float* __restrict__ w,
                                                unsigned char* __restrict__ wq) {
    const size_t i = ((size_t)blockIdx.x * 256 + threadIdx.x) * 4;
    float4 v = *(const float4*)(w + i);
    int p = __builtin_amdgcn_cvt_pk_fp8_f32(v.x, v.y, 0, false);
    p     = __builtin_amdgcn_cvt_pk_fp8_f32(v.z, v.w, p, true);
    *(int*)(wq + i) = p;
}

// ---------------------------------------------------------------------------
// Block-scaled fp8 GEMM: C[m,n] = sum_kb a_s[m,kb]*w_s[nb,kb]*(A8_blk @ B8_blk^T)
// 128x128 tile, BK=64, 4 waves (each 64x64 = 4x4 frags of 16x16x32 fp8 MFMA).
// Per 128-K block: accumulate exact fp8 partial products in accB, then fold
// into accM with the per-row scale. global_load_lds width-16 staging.
// ---------------------------------------------------------------------------
__global__ __launch_bounds__(256) void gemm_fp8_blk(
    const unsigned char* __restrict__ Aq,   // [M][K] fp8
    const unsigned char* __restrict__ Bq,   // [N][K] fp8
    const float* __restrict__ xst,          // [K/128][M] act scales (transposed)
    const float* __restrict__ wsc,          // [N/128][K/128] weight scales
    float* __restrict__ C, int M, int N, int K) {
    __shared__ unsigned char As[128 * 64];
    __shared__ unsigned char Bs[128 * 64];

    const int t    = threadIdx.x;
    const int lane = t & 63;
    const int wave = t >> 6;            // 0..3
    const int wr   = wave >> 1;         // wave row (0..1)
    const int wc   = wave & 1;          // wave col (0..1)
    const int bm   = blockIdx.y * 128;
    const int bn   = blockIdx.x * 128;
    const int KBLK = K >> 7;            // 32
    const int nb   = bn >> 7;

    // staging: 256 threads x 16B = 4096B = 64 rows x 64B per issue; 2 issues/op
    const int srow = t >> 2;            // 0..63
    const int scol = (t & 3) << 4;      // 0,16,32,48
    const unsigned char* gA = Aq + (size_t)(bm + srow) * K + scol;
    const unsigned char* gB = Bq + (size_t)(bn + srow) * K + scol;
    const int ldsoff = wave * 1024;     // wave-uniform LDS base (+ lane*16 by HW)

    // fragment read offsets (row-major [128][64] LDS tile)
    const int arow = (wr * 64 + (lane & 15)) * 64 + ((lane >> 4) << 3);
    const int brow = (wc * 64 + (lane & 15)) * 64 + ((lane >> 4) << 3);

    f32x4 accM[4][4] = {};

    for (int kb = 0; kb < KBLK; ++kb) {
        const float wsv = wsc[nb * KBLK + kb];   // wave-uniform scalar
        f32x4 accB[4][4] = {};
#pragma unroll
        for (int half = 0; half < 2; ++half) {
            const int k0 = (kb << 7) + (half << 6);
            __syncthreads();   // WAR: everyone done reading LDS
            __builtin_amdgcn_global_load_lds(
                (const __attribute__((address_space(1))) void*)(gA + k0),
                (__attribute__((address_space(3))) void*)(As + ldsoff), 16, 0, 0);
            __builtin_amdgcn_global_load_lds(
                (const __attribute__((address_space(1))) void*)(gA + (size_t)64 * K + k0),
                (__attribute__((address_space(3))) void*)(As + 4096 + ldsoff), 16, 0, 0);
            __builtin_amdgcn_global_load_lds(
                (const __attribute__((address_space(1))) void*)(gB + k0),
                (__attribute__((address_space(3))) void*)(Bs + ldsoff), 16, 0, 0);
            __builtin_amdgcn_global_load_lds(
                (const __attribute__((address_space(1))) void*)(gB + (size_t)64 * K + k0),
                (__attribute__((address_space(3))) void*)(Bs + 4096 + ldsoff), 16, 0, 0);
            __syncthreads();   // compiler drains vmcnt before barrier

#pragma unroll
            for (int ks = 0; ks < 2; ++ks) {
                i64 a[4], b[4];
#pragma unroll
                for (int i = 0; i < 4; ++i) {
                    a[i] = *(const i64*)&As[arow + i * (16 * 64) + ks * 32];
                    b[i] = *(const i64*)&Bs[brow + i * (16 * 64) + ks * 32];
                }
#pragma unroll
                for (int i = 0; i < 4; ++i)
#pragma unroll
                    for (int j = 0; j < 4; ++j)
                        accB[i][j] = __builtin_amdgcn_mfma_f32_16x16x32_fp8_fp8(
                            a[i], b[j], accB[i][j], 0, 0, 0);
            }
        }
        // fold the exact per-block sums into the main accumulator with scales
        const float* asp = xst + (size_t)kb * M + bm + wr * 64 + ((lane >> 4) << 2);
#pragma unroll
        for (int i = 0; i < 4; ++i) {
            f32x4 as4 = *(const f32x4*)(asp + i * 16);
            f32x4 sc  = as4 * wsv;
#pragma unroll
            for (int j = 0; j < 4; ++j)
                accM[i][j] += accB[i][j] * sc;
        }
    }

    // C write: row = (lane>>4)*4 + reg, col = lane&15 (verified C/D layout)
    const int cm = bm + wr * 64 + ((lane >> 4) << 2);
    const int cn = bn + wc * 64 + (lane & 15);
#pragma unroll
    for (int i = 0; i < 4; ++i)
#pragma unroll
        for (int j = 0; j < 4; ++j) {
            float* cp = C + (size_t)(cm + i * 16) * N + (cn + j * 16);
#pragma unroll
            for (int r = 0; r < 4; ++r) cp[(size_t)r * N] = accM[i][j][r];
        }
}

extern "C" void kernel_launch(void* const* d_in, const int* in_sizes, int n_in,
                              void* d_out, int out_size, void* d_ws, size_t ws_size,
                              hipStream_t stream) {
    const float* x   = (const float*)d_in[0];   // [4096][4096] fp32
    const float* wqf = (const float*)d_in[1];   // [4096][4096] fp32 (fp8-grid values)
    const float* wsc = (const float*)d_in[2];   // [32][32] fp32
    float* out = (float*)d_out;

    const int M = 4096, N = 4096, K = 4096;

    unsigned char* xq  = (unsigned char*)d_ws;                       // 16 MB
    unsigned char* wq8 = (unsigned char*)d_ws + (size_t)M * K;       // 16 MB
    float* xst = (float*)((unsigned char*)d_ws + (size_t)M * K + (size_t)N * K); // 512 KB

    act_quant_k<<<M * (K / 128) / 8, 256, 0, stream>>>(x, xq, xst, M, K);
    wq_cvt_k<<<(N / 4) * (K / 256), 256, 0, stream>>>(wqf, wq8);
    dim3 grid(N / 128, M / 128);
    gemm_fp8_blk<<<grid, 256, 0, stream>>>(xq, wq8, xst, wsc, out, M, N, K);
}

// Round 2
// 274.723 us; speedup vs baseline: 1.1317x; 1.1317x over previous
//
#include <hip/hip_runtime.h>

typedef float f32x4 __attribute__((ext_vector_type(4)));
typedef long i64;

#define FP8_MAX 448.0f

// ---------------------------------------------------------------------------
// Activation quant: per (row, 128-elem K-block): s = max|x|/448, q = fp8(x/s).
// Writes xq [M][K] fp8 bytes and xst TRANSPOSED scales [K/128][M] (so the GEMM
// epilogue can read 4 consecutive rows' scales as one float4).
// One 32-lane half-wave per 128-elem block; float4 per lane.
// ---------------------------------------------------------------------------
__global__ __launch_bounds__(256) void act_quant_k(const float* __restrict__ x,
                                                   unsigned char* __restrict__ xq,
                                                   float* __restrict__ xst,
                                                   int M, int K) {
    const int t   = threadIdx.x;
    const int qb  = blockIdx.x * 8 + (t >> 5);   // global 128-block id
    const int l32 = t & 31;
    const int row = qb >> 5;                     // K/128 == 32 blocks per row
    const int kb  = qb & 31;
    const size_t base = (size_t)row * K + (size_t)kb * 128 + (size_t)l32 * 4;

    float4 v = *(const float4*)(x + base);
    float am = fmaxf(fmaxf(fabsf(v.x), fabsf(v.y)), fmaxf(fabsf(v.z), fabsf(v.w)));
#pragma unroll
    for (int off = 1; off < 32; off <<= 1)
        am = fmaxf(am, __shfl_xor(am, off, 64));

    const float s = am / FP8_MAX;                // fp32 IEEE div, matches reference
    const float q0 = v.x / s, q1 = v.y / s, q2 = v.z / s, q3 = v.w / s;
    int p = __builtin_amdgcn_cvt_pk_fp8_f32(q0, q1, 0, false);
    p     = __builtin_amdgcn_cvt_pk_fp8_f32(q2, q3, p, true);
    *(int*)(xq + base) = p;
    if (l32 == 0) xst[(size_t)kb * M + row] = s;
}

// ---------------------------------------------------------------------------
// Weight fp32 -> fp8 byte conversion (values are already on the e4m3 grid,
// so this conversion is exact).
// ---------------------------------------------------------------------------
__global__ __launch_bounds__(256) void wq_cvt_k(const float* __restrict__ w,
                                                unsigned char* __restrict__ wq) {
    const size_t i = ((size_t)blockIdx.x * 256 + threadIdx.x) * 4;
    float4 v = *(const float4*)(w + i);
    int p = __builtin_amdgcn_cvt_pk_fp8_f32(v.x, v.y, 0, false);
    p     = __builtin_amdgcn_cvt_pk_fp8_f32(v.z, v.w, p, true);
    *(int*)(wq + i) = p;
}

// ---------------------------------------------------------------------------
// Block-scaled fp8 GEMM: C[m,n] = sum_kb a_s[m,kb]*w_s[nb,kb]*(A8_blk @ B8_blk^T)
// 128x128 tile, BK=64, 4 waves (each 64x64 = 4x4 frags of 16x16x32 fp8 MFMA).
// Per 128-K block: accumulate exact fp8 partial products in accB, then fold
// into accM with the per-row scale. global_load_lds width-16 staging.
//
// LDS swizzle (bank-conflict fix, rule 21 both-sides): logical tile is
// [128 rows][64 bytes]; physical byte = row*64 + (col ^ (((row>>1)&3)<<4)).
// Staging keeps the LDS dest LINEAR and pre-swizzles the per-lane GLOBAL
// source column; ds_read applies the same XOR. 16B-unit XOR preserves the
// global_load_lds 16B write granularity.
// ---------------------------------------------------------------------------
__global__ __launch_bounds__(256) void gemm_fp8_blk(
    const unsigned char* __restrict__ Aq,   // [M][K] fp8
    const unsigned char* __restrict__ Bq,   // [N][K] fp8
    const float* __restrict__ xst,          // [K/128][M] act scales (transposed)
    const float* __restrict__ wsc,          // [N/128][K/128] weight scales
    float* __restrict__ C, int M, int N, int K) {
    __shared__ unsigned char As[128 * 64];
    __shared__ unsigned char Bs[128 * 64];

    const int t    = threadIdx.x;
    const int lane = t & 63;
    const int wave = t >> 6;            // 0..3
    const int wr   = wave >> 1;         // wave row (0..1)
    const int wc   = wave & 1;          // wave col (0..1)
    const int bm   = blockIdx.y * 128;
    const int bn   = blockIdx.x * 128;
    const int KBLK = K >> 7;            // 32
    const int nb   = bn >> 7;

    // staging: 256 threads x 16B = 4096B = 64 rows x 64B per issue; 2 issues/op
    // source column pre-swizzled: col16_src = (t&3) ^ ((srow>>1)&3), srow = t>>2
    const int srow   = t >> 2;          // 0..63
    const int scolsw = (((t & 3) ^ ((t >> 3) & 3)) << 4);
    const unsigned char* gA = Aq + (size_t)(bm + srow) * K + scolsw;
    const unsigned char* gB = Bq + (size_t)(bn + srow) * K + scolsw;
    const int ldsoff = wave * 1024;     // wave-uniform LDS base (+ lane*16 by HW)

    // fragment read addressing (swizzled)
    const int r15 = lane & 15;
    const int g   = lane >> 4;                    // k-group 0..3
    const int sX  = (r15 >> 1) & 3;               // swizzle nibble: (row>>1)&3, row-const per lane
    const int sub = (g & 1) << 3;                 // 0 or 8 bytes within 16B unit
    const int c0  = g >> 1;                       // logical col16 at ks=0
    const int pcs[2] = { ((c0 ^ sX) << 4) + sub,            // ks=0 physical col
                         (((c0 + 2) ^ sX) << 4) + sub };    // ks=1 physical col
    const int aBase = (wr * 64 + r15) * 64;
    const int bBase = (wc * 64 + r15) * 64;

    f32x4 accM[4][4] = {};

    for (int kb = 0; kb < KBLK; ++kb) {
        const float wsv = wsc[nb * KBLK + kb];   // wave-uniform scalar
        f32x4 accB[4][4] = {};
#pragma unroll
        for (int half = 0; half < 2; ++half) {
            const int k0 = (kb << 7) + (half << 6);
            __syncthreads();   // WAR: everyone done reading LDS
            __builtin_amdgcn_global_load_lds(
                (const __attribute__((address_space(1))) void*)(gA + k0),
                (__attribute__((address_space(3))) void*)(As + ldsoff), 16, 0, 0);
            __builtin_amdgcn_global_load_lds(
                (const __attribute__((address_space(1))) void*)(gA + (size_t)64 * K + k0),
                (__attribute__((address_space(3))) void*)(As + 4096 + ldsoff), 16, 0, 0);
            __builtin_amdgcn_global_load_lds(
                (const __attribute__((address_space(1))) void*)(gB + k0),
                (__attribute__((address_space(3))) void*)(Bs + ldsoff), 16, 0, 0);
            __builtin_amdgcn_global_load_lds(
                (const __attribute__((address_space(1))) void*)(gB + (size_t)64 * K + k0),
                (__attribute__((address_space(3))) void*)(Bs + 4096 + ldsoff), 16, 0, 0);
            __syncthreads();   // compiler drains vmcnt before barrier

#pragma unroll
            for (int ks = 0; ks < 2; ++ks) {
                const int pc = pcs[ks];
                i64 a[4], b[4];
#pragma unroll
                for (int i = 0; i < 4; ++i) {
                    a[i] = *(const i64*)&As[aBase + i * 1024 + pc];
                    b[i] = *(const i64*)&Bs[bBase + i * 1024 + pc];
                }
#pragma unroll
                for (int i = 0; i < 4; ++i)
#pragma unroll
                    for (int j = 0; j < 4; ++j)
                        accB[i][j] = __builtin_amdgcn_mfma_f32_16x16x32_fp8_fp8(
                            a[i], b[j], accB[i][j], 0, 0, 0);
            }
        }
        // fold the exact per-block sums into the main accumulator with scales
        const float* asp = xst + (size_t)kb * M + bm + wr * 64 + ((lane >> 4) << 2);
#pragma unroll
        for (int i = 0; i < 4; ++i) {
            f32x4 as4 = *(const f32x4*)(asp + i * 16);
            f32x4 sc  = as4 * wsv;
#pragma unroll
            for (int j = 0; j < 4; ++j)
                accM[i][j] += accB[i][j] * sc;
        }
    }

    // C write: row = (lane>>4)*4 + reg, col = lane&15 (verified C/D layout)
    const int cm = bm + wr * 64 + ((lane >> 4) << 2);
    const int cn = bn + wc * 64 + (lane & 15);
#pragma unroll
    for (int i = 0; i < 4; ++i)
#pragma unroll
        for (int j = 0; j < 4; ++j) {
            float* cp = C + (size_t)(cm + i * 16) * N + (cn + j * 16);
#pragma unroll
            for (int r = 0; r < 4; ++r) cp[(size_t)r * N] = accM[i][j][r];
        }
}

extern "C" void kernel_launch(void* const* d_in, const int* in_sizes, int n_in,
                              void* d_out, int out_size, void* d_ws, size_t ws_size,
                              hipStream_t stream) {
    const float* x   = (const float*)d_in[0];   // [4096][4096] fp32
    const float* wqf = (const float*)d_in[1];   // [4096][4096] fp32 (fp8-grid values)
    const float* wsc = (const float*)d_in[2];   // [32][32] fp32
    float* out = (float*)d_out;

    const int M = 4096, N = 4096, K = 4096;

    unsigned char* xq  = (unsigned char*)d_ws;                       // 16 MB
    unsigned char* wq8 = (unsigned char*)d_ws + (size_t)M * K;       // 16 MB
    float* xst = (float*)((unsigned char*)d_ws + (size_t)M * K + (size_t)N * K); // 512 KB

    act_quant_k<<<M * (K / 128) / 8, 256, 0, stream>>>(x, xq, xst, M, K);
    wq_cvt_k<<<(N / 4) * (K / 256), 256, 0, stream>>>(wqf, wq8);
    dim3 grid(N / 128, M / 128);
    gemm_fp8_blk<<<grid, 256, 0, stream>>>(xq, wq8, xst, wsc, out, M, N, K);
}

// Round 4
// 177.543 us; speedup vs baseline: 1.7512x; 1.5474x over previous
//
#include <hip/hip_runtime.h>

typedef float f32x4 __attribute__((ext_vector_type(4)));
typedef long i64;

#define FP8_MAX 448.0f

// ---------------------------------------------------------------------------
// Activation quant: per (row, 128-elem K-block): s = max|x|/448, q = fp8(x/s).
// Writes xq [M][K] fp8 bytes and xst TRANSPOSED scales [K/128][M].
// ---------------------------------------------------------------------------
__global__ __launch_bounds__(256) void act_quant_k(const float* __restrict__ x,
                                                   unsigned char* __restrict__ xq,
                                                   float* __restrict__ xst,
                                                   int M, int K) {
    const int t   = threadIdx.x;
    const int qb  = blockIdx.x * 8 + (t >> 5);   // global 128-block id
    const int l32 = t & 31;
    const int row = qb >> 5;                     // K/128 == 32 blocks per row
    const int kb  = qb & 31;
    const size_t base = (size_t)row * K + (size_t)kb * 128 + (size_t)l32 * 4;

    float4 v = *(const float4*)(x + base);
    float am = fmaxf(fmaxf(fabsf(v.x), fabsf(v.y)), fmaxf(fabsf(v.z), fabsf(v.w)));
#pragma unroll
    for (int off = 1; off < 32; off <<= 1)
        am = fmaxf(am, __shfl_xor(am, off, 64));

    const float s = am / FP8_MAX;                // fp32 IEEE div, matches reference
    const float q0 = v.x / s, q1 = v.y / s, q2 = v.z / s, q3 = v.w / s;
    int p = __builtin_amdgcn_cvt_pk_fp8_f32(q0, q1, 0, false);
    p     = __builtin_amdgcn_cvt_pk_fp8_f32(q2, q3, p, true);
    *(int*)(xq + base) = p;
    if (l32 == 0) xst[(size_t)kb * M + row] = s;
}

// ---------------------------------------------------------------------------
// Weight fp32 -> fp8 byte conversion (values already on the e4m3 grid: exact).
// ---------------------------------------------------------------------------
__global__ __launch_bounds__(256) void wq_cvt_k(const float* __restrict__ w,
                                                unsigned char* __restrict__ wq) {
    const size_t i = ((size_t)blockIdx.x * 256 + threadIdx.x) * 4;
    float4 v = *(const float4*)(w + i);
    int p = __builtin_amdgcn_cvt_pk_fp8_f32(v.x, v.y, 0, false);
    p     = __builtin_amdgcn_cvt_pk_fp8_f32(v.z, v.w, p, true);
    *(int*)(wq + i) = p;
}

// ---------------------------------------------------------------------------
// Block-scaled fp8 GEMM, 128x128 tile, BK=64, 4 waves (64x64 each, 4x4 frags
// of 16x16x32 fp8 MFMA). T3-min pipeline: double-buffered LDS, STAGE of the
// next 64-K tile issued BEFORE compute of the current one, raw s_barrier with
// explicit vmcnt(0) AFTER the MFMA cluster (loads fly during compute).
// Per 128-K scale block: exact fp8 partial sums in accB (first MFMA uses a
// persistent zero C operand -> no per-block zero-init), folded into accM with
// a_s[m,kb]*w_s[nb,kb].
//
// LDS swizzle (both-sides, rule 21): logical [128 rows][64B];
// physical byte = row*64 + (col ^ (((row>>1)&3)<<4)). Staging keeps the LDS
// dest LINEAR and pre-swizzles the per-lane GLOBAL source column; ds_read
// applies the same XOR.
// ---------------------------------------------------------------------------
__global__ __launch_bounds__(256) void gemm_fp8_blk(
    const unsigned char* __restrict__ Aq,   // [M][K] fp8
    const unsigned char* __restrict__ Bq,   // [N][K] fp8
    const float* __restrict__ xst,          // [K/128][M] act scales (transposed)
    const float* __restrict__ wsc,          // [N/128][K/128] weight scales
    float* __restrict__ C, int M, int N, int K) {
    __shared__ unsigned char As[2][8192];   // [buf][128 rows x 64 B]
    __shared__ unsigned char Bs[2][8192];

    const int t    = threadIdx.x;
    const int lane = t & 63;
    const int wave = t >> 6;            // 0..3
    const int wr   = wave >> 1;         // wave row (0..1)
    const int wc   = wave & 1;          // wave col (0..1)
    const int bm   = blockIdx.y * 128;
    const int bn   = blockIdx.x * 128;
    const int KBLK = K >> 7;            // 32 scale blocks (2 tiles of 64-K each)
    const int nb   = bn >> 7;

    // staging: 256 threads x 16B = 4096B = 64 rows x 64B per issue; 2/operand
    const int srow   = t >> 2;          // 0..63
    const int scolsw = (((t & 3) ^ ((t >> 3) & 3)) << 4);   // pre-swizzled src col
    const unsigned char* gA = Aq + (size_t)(bm + srow) * K + scolsw;
    const unsigned char* gB = Bq + (size_t)(bn + srow) * K + scolsw;
    const int ldsoff = wave * 1024;     // wave-uniform LDS base (+ lane*16 by HW)

    // fragment read addressing (swizzled)
    const int r15 = lane & 15;
    const int g   = lane >> 4;                    // k-group 0..3
    const int sX  = (r15 >> 1) & 3;               // (row>>1)&3, row-const per lane
    const int sub = (g & 1) << 3;                 // 0 or 8 bytes within 16B unit
    const int c0  = g >> 1;                       // logical col16 at ks=0
    const int pcs[2] = { ((c0 ^ sX) << 4) + sub,
                         (((c0 + 2) ^ sX) << 4) + sub };
    const int aBase = (wr * 64 + r15) * 64;
    const int bBase = (wc * 64 + r15) * 64;

#define STAGE(BUF, KH) do {                                                       \
        const int k0_ = (KH) << 6;                                                \
        __builtin_amdgcn_global_load_lds(                                         \
            (const __attribute__((address_space(1))) void*)(gA + k0_),            \
            (__attribute__((address_space(3))) void*)(&As[BUF][0] + ldsoff), 16, 0, 0); \
        __builtin_amdgcn_global_load_lds(                                         \
            (const __attribute__((address_space(1))) void*)(gA + (size_t)64 * K + k0_), \
            (__attribute__((address_space(3))) void*)(&As[BUF][4096] + ldsoff), 16, 0, 0); \
        __builtin_amdgcn_global_load_lds(                                         \
            (const __attribute__((address_space(1))) void*)(gB + k0_),            \
            (__attribute__((address_space(3))) void*)(&Bs[BUF][0] + ldsoff), 16, 0, 0); \
        __builtin_amdgcn_global_load_lds(                                         \
            (const __attribute__((address_space(1))) void*)(gB + (size_t)64 * K + k0_), \
            (__attribute__((address_space(3))) void*)(&Bs[BUF][4096] + ldsoff), 16, 0, 0); \
    } while (0)

    // raw barrier: vmcnt(0) drains OUR 4 staged loads (issued one compute-phase
    // ago, already landed); asm "memory" clobbers fence compiler memory-op
    // motion on both sides of the barrier.
#define SYNC() do {                                                               \
        asm volatile("s_waitcnt vmcnt(0)" ::: "memory");                          \
        __builtin_amdgcn_s_barrier();                                             \
        asm volatile("" ::: "memory");                                            \
    } while (0)

#define COMPUTE(BUF, FIRST) do {                                                  \
        _Pragma("unroll")                                                         \
        for (int ks = 0; ks < 2; ++ks) {                                          \
            const int pc = pcs[ks];                                               \
            i64 a_[4], b_[4];                                                     \
            _Pragma("unroll")                                                     \
            for (int i = 0; i < 4; ++i) {                                         \
                a_[i] = *(const i64*)&As[BUF][aBase + i * 1024 + pc];             \
                b_[i] = *(const i64*)&Bs[BUF][bBase + i * 1024 + pc];             \
            }                                                                     \
            _Pragma("unroll")                                                     \
            for (int i = 0; i < 4; ++i)                                           \
                _Pragma("unroll")                                                 \
                for (int j = 0; j < 4; ++j)                                       \
                    accB[i][j] = __builtin_amdgcn_mfma_f32_16x16x32_fp8_fp8(      \
                        a_[i], b_[j], ((FIRST) && ks == 0) ? z4 : accB[i][j],     \
                        0, 0, 0);                                                 \
        }                                                                         \
    } while (0)

#define FOLD(KB) do {                                                             \
        const float wsv_ = wsc[nb * KBLK + (KB)];                                 \
        const float* asp_ = xst + (size_t)(KB) * M + bm + wr * 64 + (g << 2);     \
        _Pragma("unroll")                                                         \
        for (int i = 0; i < 4; ++i) {                                             \
            f32x4 sc_ = (*(const f32x4*)(asp_ + i * 16)) * wsv_;                  \
            _Pragma("unroll")                                                     \
            for (int j = 0; j < 4; ++j)                                           \
                accM[i][j] += accB[i][j] * sc_;                                   \
        }                                                                         \
    } while (0)

    f32x4 accM[4][4] = {};
    f32x4 accB[4][4];                       // init'd by z4-C MFMA, no reg writes
    const f32x4 z4 = {0.f, 0.f, 0.f, 0.f};

    STAGE(0, 0);
    SYNC();

#pragma unroll 1
    for (int kb = 0; kb < KBLK; ++kb) {
        // even tile (buf 0): prefetch odd tile, compute even, start fresh accB
        STAGE(1, 2 * kb + 1);
        COMPUTE(0, true);
        SYNC();
        // odd tile (buf 1): prefetch next pair's even tile, compute, fold
        if (kb != KBLK - 1) STAGE(0, 2 * kb + 2);
        COMPUTE(1, false);
        FOLD(kb);
        SYNC();
    }

    // C write: row = (lane>>4)*4 + reg, col = lane&15 (verified C/D layout)
    const int cm = bm + wr * 64 + (g << 2);
    const int cn = bn + wc * 64 + r15;
#pragma unroll
    for (int i = 0; i < 4; ++i)
#pragma unroll
        for (int j = 0; j < 4; ++j) {
            float* cp = C + (size_t)(cm + i * 16) * N + (cn + j * 16);
#pragma unroll
            for (int r = 0; r < 4; ++r) cp[(size_t)r * N] = accM[i][j][r];
        }
#undef STAGE
#undef SYNC
#undef COMPUTE
#undef FOLD
}

extern "C" void kernel_launch(void* const* d_in, const int* in_sizes, int n_in,
                              void* d_out, int out_size, void* d_ws, size_t ws_size,
                              hipStream_t stream) {
    const float* x   = (const float*)d_in[0];   // [4096][4096] fp32
    const float* wqf = (const float*)d_in[1];   // [4096][4096] fp32 (fp8-grid values)
    const float* wsc = (const float*)d_in[2];   // [32][32] fp32
    float* out = (float*)d_out;

    const int M = 4096, N = 4096, K = 4096;

    unsigned char* xq  = (unsigned char*)d_ws;                       // 16 MB
    unsigned char* wq8 = (unsigned char*)d_ws + (size_t)M * K;       // 16 MB
    float* xst = (float*)((unsigned char*)d_ws + (size_t)M * K + (size_t)N * K); // 512 KB

    act_quant_k<<<M * (K / 128) / 8, 256, 0, stream>>>(x, xq, xst, M, K);
    wq_cvt_k<<<(N / 4) * (K / 256), 256, 0, stream>>>(wqf, wq8);
    dim3 grid(N / 128, M / 128);
    gemm_fp8_blk<<<grid, 256, 0, stream>>>(xq, wq8, xst, wsc, out, M, N, K);
}